// Round 8
// baseline (244.188 us; speedup 1.0000x reference)
//
#include <hip/hip_runtime.h>
#include <math.h>

#define T_DIM 4096
#define B_DIM 8
#define C_DIM 1024
#define H_DIM 16
#define K_DIM 31
#define NT 32                  // taps padded to 32 (tp[0]=0): all slot math mod-32
#define L_SEG 128              // t-outputs per thread (32 segments over T)
#define BLOCK 256
#define DP 8                   // prefetch ring depth
#define STRIDE (B_DIM * C_DIM) // 8192 floats between consecutive t

// R11: zero-LDS streaming-register FIR. Every staged-tile variant (R5-R10)
// alternates a memory-only burst with a memory-idle compute phase per wave
// and pins at ~2.5 TB/s. This kernel issues 1 coalesced load + 30 FMA +
// 1 store per step, continuously, per wave — the m13-copy/AITER profile.
// out[t] = sum_{k=1..31} tp[k]*x[t-31+k]  (tp[k]=softmax(w)[k-1], tp[0]=0).
// When x[u] arrives: completes out=u (tap 31), feeds out=u+j (tap 31-j,
// j=1..30), opens out=u+31 with 0 (tap 0 = 0). Slot = out-index & 31:
// compile-time inside the unrolled 32-step body (template recursion: the
// R4 lesson — any runtime index on acc[]/xr[] goes to scratch).

// ---- warm-up step M (u = t0-31+M, slot base (u&31) = M+1): no stores,
// only contributions to out >= t0 (j >= 31-M). Reissues ring slot. ----
template <int M>
__device__ __forceinline__ void warm(const float* pw,   // x + (t0-31)*STRIDE + cc
                                     float (&xr)[DP],
                                     const float (&tp)[NT],
                                     float (&acc)[NT]) {
    if constexpr (M < 31) {
        const float v = xr[(M + 1) & 7];
        #pragma unroll
        for (int j = 1; j <= 30; ++j) {
            if (j >= 31 - M)
                acc[(M + 1 + j) & 31] = fmaf(tp[31 - j], v, acc[(M + 1 + j) & 31]);
        }
        xr[(M + 1) & 7] = pw[(long)(M + DP) * STRIDE];   // load x[u+8]
        warm<M + 1>(pw, xr, tp, acc);
    }
}

// ---- main step SB of a 32-row body (tb ≡ 0 mod 32; u = tb+SB) ----
template <int SB, bool LAST>
__device__ __forceinline__ void bstep(const float* pin,  // x   + tb*STRIDE + cc
                                      float* pout,       // out + tb*STRIDE + cc
                                      float (&xr)[DP],
                                      const float (&tp)[NT],
                                      float (&acc)[NT]) {
    if constexpr (SB < 32) {
        const float v = xr[SB & 7];                       // waits vmcnt(counted)
        pout[(long)SB * STRIDE] = fmaf(tp[31], v, acc[SB]);   // out=u complete
        #pragma unroll
        for (int j = 1; j <= 30; ++j)
            acc[(SB + j) & 31] = fmaf(tp[31 - j], v, acc[(SB + j) & 31]);
        acc[(SB + 31) & 31] = 0.0f;                       // open out=u+31 (tap0=0)
        if constexpr (!LAST || SB < 24)                   // never read past segment
            xr[SB & 7] = pin[(long)(SB + DP) * STRIDE];   // load x[u+8]
        bstep<SB + 1, LAST>(pin, pout, xr, tp, acc);
    }
}

__global__ __launch_bounds__(BLOCK, 4) void lightconv_kernel(
    const float* __restrict__ x,
    const float* __restrict__ w,
    float* __restrict__ out)
{
    const int tid    = threadIdx.x;
    const int wv     = tid >> 6;
    const int colBlk = blockIdx.x;              // 0..31  (B*C / 256 columns)
    const int tseg   = blockIdx.y;              // 0..31  (T / 128)
    const int cc     = colBlk * BLOCK + tid;    // flat b*C + c
    const long t0    = (long)tseg * L_SEG;      // ≡ 0 mod 32

    // ---- redundant per-wave softmax -> SGPR taps (wave spans one head) ----
    float tp[NT];
    {
        const float* wr = w + (((colBlk & 3) << 2) + wv) * K_DIM;
        float tv[K_DIM];
        float m = -1e30f;
        #pragma unroll
        for (int k = 0; k < K_DIM; ++k) { tv[k] = wr[k]; m = fmaxf(m, tv[k]); }
        float s = 0.f;
        #pragma unroll
        for (int k = 0; k < K_DIM; ++k) { tv[k] = __expf(tv[k] - m); s += tv[k]; }
        const float inv = 1.0f / s;
        tp[0] = 0.0f;
        #pragma unroll
        for (int k = 0; k < K_DIM; ++k)
            tp[k + 1] = __int_as_float(__builtin_amdgcn_readfirstlane(
                            __float_as_int(tv[k] * inv)));
    }

    // ---- 32 streaming accumulators, all zeroed ----
    float acc[NT];
    #pragma unroll
    for (int i = 0; i < NT; ++i) acc[i] = 0.0f;

    // ---- prefill ring + warm-up (31 history rows; tseg==0: history = 0) ----
    float xr[DP];
    if (tseg > 0) {                              // wave-uniform branch
        const float* pw = x + (t0 - 31) * STRIDE + cc;
        #pragma unroll
        for (int m = 0; m < DP; ++m)             // x[t0-31 .. t0-24]
            xr[(m + 1) & 7] = pw[(long)m * STRIDE];
        warm<0>(pw, xr, tp, acc);                // ends having loaded x[t0..t0+7]
    } else {                                     // history is zero: accs stay 0;
        #pragma unroll                           // just prime ring with x[0..7]
        for (int m = 0; m < DP; ++m)
            xr[m] = x[(long)m * STRIDE + cc];    // u=m -> slot m&7 = m
    }

    // ---- 128 main steps: 3 full bodies + tail body (prefetch stops at seg end)
    const float* pin = x   + t0 * STRIDE + cc;
    float*       pout = out + t0 * STRIDE + cc;
    #pragma unroll 1
    for (int b = 0; b < 3; ++b) {
        bstep<0, false>(pin, pout, xr, tp, acc);
        pin  += 32 * STRIDE;
        pout += 32 * STRIDE;
    }
    bstep<0, true>(pin, pout, xr, tp, acc);
}

extern "C" void kernel_launch(void* const* d_in, const int* in_sizes, int n_in,
                              void* d_out, int out_size, void* d_ws, size_t ws_size,
                              hipStream_t stream) {
    const float* x = (const float*)d_in[0];    // [T, B, C] fp32
    const float* w = (const float*)d_in[1];    // [H, K]    fp32
    float* out = (float*)d_out;                // [T, B, C] fp32

    dim3 grid((B_DIM * C_DIM) / BLOCK, T_DIM / L_SEG);   // (32, 32)
    lightconv_kernel<<<grid, BLOCK, 0, stream>>>(x, w, out);
}

// Round 9
// 238.030 us; speedup vs baseline: 1.0259x; 1.0259x over previous
//
#include <hip/hip_runtime.h>
#include <math.h>

#define T_DIM 4096
#define B_DIM 8
#define C_DIM 1024
#define H_DIM 16
#define K_DIM 31
#define NT 32                  // taps padded to 32 (tp[0]=0): slot math mod-32
#define L_SEG 128              // t-outputs per thread (32 segments over T)
#define BLOCK 256
#define DP 16                  // prefetch ring depth (mod-16 slots)
#define STRIDE (B_DIM * C_DIM) // 8192 floats between consecutive t

typedef __attribute__((ext_vector_type(2))) float f32x2;

// R12: persistent dense-band streaming FIR, 2 columns/thread.
//  - grid = 512 blocks = EXACTLY 2 blocks/CU resident: no completion-driven
//    relaunch ever -> the 32 t-segment bands stay phase-coherent and the
//    instantaneous HBM footprint is 32 dense full-width (32 KB/row) sliding
//    windows (the profile of the 6.7 TB/s fill / 6.3 TB/s copy), instead of
//    the fragmenting random patches of R5-R11.
//  - 2 consecutive cols/thread: dwordx2 (512 B/wave chunks), half the issue
//    + address overhead per element. col0 even => both cols same head.
//  - DP=16 ring: 8 waves/CU x 16 x 512 B = 64 KB/CU in flight (~3x
//    Little's-law for 900 ns HBM latency at our per-CU BW share).
// Math identical to R11 (PASSED): out[t] = sum_{k=1..31} tp[k]*x[t-31+k],
// tp[k]=softmax(w)[k-1], tp[0]=0. All acc/ring/tap indices compile-time
// (template recursion; R4 scratch lesson).

// ---- warm-up step M (u = t0-31+M): contributions to out >= t0 only ----
template <int M>
__device__ __forceinline__ void warm(const float* pw,   // x + (t0-31)*STRIDE + col0
                                     f32x2 (&xr)[DP],
                                     const float (&tp)[NT],
                                     f32x2 (&acc)[NT]) {
    if constexpr (M < 31) {
        const f32x2 v = xr[(M + 1) & 15];
        #pragma unroll
        for (int j = 1; j <= 30; ++j) {
            if (j >= 31 - M) {
                acc[(M + 1 + j) & 31].x = fmaf(tp[31 - j], v.x, acc[(M + 1 + j) & 31].x);
                acc[(M + 1 + j) & 31].y = fmaf(tp[31 - j], v.y, acc[(M + 1 + j) & 31].y);
            }
        }
        xr[(M + 1) & 15] = *(const f32x2*)(pw + (long)(M + DP) * STRIDE);
        warm<M + 1>(pw, xr, tp, acc);
    }
}

// ---- main step SB of a 32-row body (tb ≡ 0 mod 32; u = tb+SB) ----
template <int SB, bool LAST>
__device__ __forceinline__ void bstep(const float* pin,  // x   + tb*STRIDE + col0
                                      float* pout,       // out + tb*STRIDE + col0
                                      f32x2 (&xr)[DP],
                                      const float (&tp)[NT],
                                      f32x2 (&acc)[NT]) {
    if constexpr (SB < 32) {
        const f32x2 v = xr[SB & 15];               // counted vmcnt wait
        f32x2 o;
        o.x = fmaf(tp[31], v.x, acc[SB].x);        // out = u complete
        o.y = fmaf(tp[31], v.y, acc[SB].y);
        *(f32x2*)(pout + (long)SB * STRIDE) = o;
        #pragma unroll
        for (int j = 1; j <= 30; ++j) {
            acc[(SB + j) & 31].x = fmaf(tp[31 - j], v.x, acc[(SB + j) & 31].x);
            acc[(SB + j) & 31].y = fmaf(tp[31 - j], v.y, acc[(SB + j) & 31].y);
        }
        acc[(SB + 31) & 31].x = 0.0f;              // open out = u+31 (tap0 = 0)
        acc[(SB + 31) & 31].y = 0.0f;
        if constexpr (!LAST || SB < 32 - DP)       // never read past the segment
            xr[SB & 15] = *(const f32x2*)(pin + (long)(SB + DP) * STRIDE);
        bstep<SB + 1, LAST>(pin, pout, xr, tp, acc);
    }
}

__global__ __launch_bounds__(BLOCK, 2) void lightconv_kernel(
    const float* __restrict__ x,
    const float* __restrict__ w,
    float* __restrict__ out)
{
    const int tid    = threadIdx.x;
    const int colBlk = blockIdx.x;                  // 0..15 (B*C / 512)
    const int tseg   = blockIdx.y;                  // 0..31 (T / 128)
    const int col0   = (colBlk * BLOCK + tid) * 2;  // even flat b*C + c
    const long t0    = (long)tseg * L_SEG;          // ≡ 0 mod 32

    // ---- per-lane softmax -> VGPR taps (both cols share one head) ----
    float tp[NT];
    {
        const int head = (col0 >> 6) & 15;
        const float* wr = w + head * K_DIM;
        float tv[K_DIM];
        float m = -1e30f;
        #pragma unroll
        for (int k = 0; k < K_DIM; ++k) { tv[k] = wr[k]; m = fmaxf(m, tv[k]); }
        float s = 0.f;
        #pragma unroll
        for (int k = 0; k < K_DIM; ++k) { tv[k] = __expf(tv[k] - m); s += tv[k]; }
        const float inv = 1.0f / s;
        tp[0] = 0.0f;
        #pragma unroll
        for (int k = 0; k < K_DIM; ++k) tp[k + 1] = tv[k] * inv;
    }

    // ---- 32 streaming accumulator pairs, zeroed ----
    f32x2 acc[NT];
    #pragma unroll
    for (int i = 0; i < NT; ++i) { acc[i].x = 0.0f; acc[i].y = 0.0f; }

    // ---- prefill ring + warm-up (31 history rows; tseg==0: history = 0) ----
    f32x2 xr[DP];
    if (tseg > 0) {                                 // wave-uniform branch
        const float* pw = x + (t0 - 31) * STRIDE + col0;
        #pragma unroll
        for (int m = 0; m < DP; ++m)                // u = t0-31+m, slot (m+1)&15
            xr[(m + 1) & 15] = *(const f32x2*)(pw + (long)m * STRIDE);
        warm<0>(pw, xr, tp, acc);                   // ends holding x[t0..t0+15]
    } else {                                        // history zero: accs stay 0
        #pragma unroll
        for (int m = 0; m < DP; ++m)                // u = m -> slot m
            xr[m] = *(const f32x2*)(x + (long)m * STRIDE + col0);
    }

    // ---- 128 main steps: 3 full bodies + tail (prefetch stops at seg end) ----
    const float* pin  = x   + t0 * STRIDE + col0;
    float*       pout = out + t0 * STRIDE + col0;
    #pragma unroll 1
    for (int b = 0; b < 3; ++b) {
        bstep<0, false>(pin, pout, xr, tp, acc);
        pin  += 32 * STRIDE;
        pout += 32 * STRIDE;
    }
    bstep<0, true>(pin, pout, xr, tp, acc);
}

extern "C" void kernel_launch(void* const* d_in, const int* in_sizes, int n_in,
                              void* d_out, int out_size, void* d_ws, size_t ws_size,
                              hipStream_t stream) {
    const float* x = (const float*)d_in[0];    // [T, B, C] fp32
    const float* w = (const float*)d_in[1];    // [H, K]    fp32
    float* out = (float*)d_out;                // [T, B, C] fp32

    dim3 grid((B_DIM * C_DIM) / (BLOCK * 2), T_DIM / L_SEG);   // (16, 32)
    lightconv_kernel<<<grid, BLOCK, 0, stream>>>(x, w, out);
}